// Round 1
// baseline (174.736 us; speedup 1.0000x reference)
//
#include <hip/hip_runtime.h>
#include <hip/hip_bf16.h>

typedef __attribute__((ext_vector_type(8))) short short8;   // bf16x8 MFMA frag
typedef __attribute__((ext_vector_type(4))) float f32x4;    // fp32x4 acc

#define B_  8
#define T_  2048
#define E_  1024
#define H_  64
#define SCALE 0.03125f   // 1024^-0.5

__device__ inline unsigned short f2bf(float f) {
    unsigned int u = __builtin_bit_cast(unsigned int, f);
    unsigned int r = (u + 0x7FFFu + ((u >> 16) & 1u)) >> 16;   // RNE
    return (unsigned short)r;
}
__device__ inline unsigned int packbf(float lo, float hi) {
    return (unsigned int)f2bf(lo) | ((unsigned int)f2bf(hi) << 16);
}

// ---------------- kernel 0: W fp32 [1024][64] -> Wt bf16 [192][1024] (transposed) ----
// rows 0-63 = Wq cols, 64-127 = Wk, 128-191 = Wv
__global__ __launch_bounds__(256) void prep_w(const float* __restrict__ Wq,
                                              const float* __restrict__ Wk,
                                              const float* __restrict__ Wv,
                                              unsigned short* __restrict__ Wt) {
    int c = blockIdx.x;            // 0..191
    int wsel = c >> 6, n = c & 63;
    const float* W = (wsel == 0) ? Wq : (wsel == 1) ? Wk : Wv;
    for (int k = threadIdx.x; k < E_; k += 256)
        Wt[(long)c * E_ + k] = f2bf(W[(long)k * H_ + n]);
}

// ---------------- kernel 1: QKV GEMM  [16384,1024] @ [1024,192] --------------------
// block = 32 rows, 4 waves: wave = (row-stripe rs = w&1, col-half ch = w>>1: 96 cols)
// outputs: qb,kb bf16 [b][t][64] row-major; v -> vt bf16 [b][h][t] (transposed)
__global__ __launch_bounds__(256) void qkv_gemm(const float* __restrict__ x,
                                                const unsigned short* __restrict__ Wt,
                                                unsigned short* __restrict__ qb,
                                                unsigned short* __restrict__ kb,
                                                unsigned short* __restrict__ vt) {
    __shared__ unsigned short xs[32 * 72];       // 32 rows x 64 k, pad 8
    __shared__ unsigned short wtile[192 * 72];   // 192 cols x 64 k, pad 8

    int tid  = threadIdx.x;
    int lane = tid & 63, w = tid >> 6;
    int rs = w & 1, ch = w >> 1;
    int l15 = lane & 15, lg = lane >> 4;
    int r0 = blockIdx.x * 32;
    int b  = r0 >> 11, tb = r0 & 2047;

    f32x4 acc[6];
    for (int i = 0; i < 6; ++i) acc[i] = (f32x4){0.f, 0.f, 0.f, 0.f};

    int xrow = tid >> 3, xk = (tid & 7) * 8;
    const float*          xp = x  + (long)(r0 + xrow) * E_ + xk;
    const unsigned short* wp = Wt + (long)xrow * E_ + xk;   // + i*32*E_ for i=0..5

    // prefetch regs (k0 = 0)
    float4 xa0 = *(const float4*)xp;
    float4 xa1 = *(const float4*)(xp + 4);
    uint4  wr[6];
    for (int i = 0; i < 6; ++i) wr[i] = *(const uint4*)(wp + (long)i * 32 * E_);

    for (int it = 0; it < 16; ++it) {
        // stage current
        uint4 xv; xv.x = packbf(xa0.x, xa0.y); xv.y = packbf(xa0.z, xa0.w);
        xv.z = packbf(xa1.x, xa1.y); xv.w = packbf(xa1.z, xa1.w);
        *(uint4*)&xs[xrow * 72 + xk] = xv;
        for (int i = 0; i < 6; ++i)
            *(uint4*)&wtile[(xrow + 32 * i) * 72 + xk] = wr[i];
        __syncthreads();

        // prefetch next
        if (it < 15) {
            int k0n = (it + 1) * 64;
            xa0 = *(const float4*)(xp + k0n);
            xa1 = *(const float4*)(xp + k0n + 4);
            for (int i = 0; i < 6; ++i)
                wr[i] = *(const uint4*)(wp + (long)i * 32 * E_ + k0n);
        }

        // compute
        int arow = 16 * rs + l15;
        for (int kk = 0; kk < 64; kk += 32) {
            short8 a = *(const short8*)&xs[arow * 72 + kk + lg * 8];
            #pragma unroll
            for (int ct = 0; ct < 6; ++ct) {
                int crow = 96 * ch + 16 * ct + l15;
                short8 bf = *(const short8*)&wtile[crow * 72 + kk + lg * 8];
                acc[ct] = __builtin_amdgcn_mfma_f32_16x16x32_bf16(a, bf, acc[ct], 0, 0, 0);
            }
        }
        __syncthreads();
    }

    // epilogue: q,k direct; v via LDS transpose
    #pragma unroll
    for (int ct = 0; ct < 6; ++ct) {
        int cg = 96 * ch + 16 * ct + l15;
        int wsel = cg >> 6, n = cg & 63;
        if (wsel < 2) {
            unsigned short* dst = (wsel == 0) ? qb : kb;
            #pragma unroll
            for (int r = 0; r < 4; ++r) {
                int t = tb + 16 * rs + lg * 4 + r;
                dst[((long)b * T_ + t) * H_ + n] = f2bf(acc[ct][r]);
            }
        }
    }
    float* vsm = (float*)wtile;   // 32 x 65 f32 = 8320B, reuse (compute done)
    if (ch == 1) {
        #pragma unroll
        for (int ct = 2; ct < 6; ++ct) {
            int n = (96 + 16 * ct + l15) & 63;
            #pragma unroll
            for (int r = 0; r < 4; ++r) {
                int tl = 16 * rs + lg * 4 + r;
                vsm[tl * 65 + n] = acc[ct][r];
            }
        }
    }
    __syncthreads();
    {
        int h = tid >> 2, tc = (tid & 3) * 8;
        uint4 o;
        o.x = packbf(vsm[(tc + 0) * 65 + h], vsm[(tc + 1) * 65 + h]);
        o.y = packbf(vsm[(tc + 2) * 65 + h], vsm[(tc + 3) * 65 + h]);
        o.z = packbf(vsm[(tc + 4) * 65 + h], vsm[(tc + 5) * 65 + h]);
        o.w = packbf(vsm[(tc + 6) * 65 + h], vsm[(tc + 7) * 65 + h]);
        *(uint4*)&vt[((long)b * H_ + h) * T_ + tb + tc] = o;
    }
}

// ---------------- kernel 2: per-key-column max & sum over queries t>=s --------------
// wave owns 16 columns; online (M,d) over 16-row score tiles; balanced pairing
__global__ __launch_bounds__(256) void col_stats(const unsigned short* __restrict__ qb,
                                                 const unsigned short* __restrict__ kb,
                                                 float* __restrict__ colM,
                                                 float* __restrict__ colR) {
    int tid = threadIdx.x, lane = tid & 63, w = tid >> 6;
    int b = blockIdx.x >> 5, j = blockIdx.x & 31;
    int c16 = (w == 0) ? 2 * j : (w == 1) ? 127 - 2 * j : (w == 2) ? 2 * j + 1 : 126 - 2 * j;
    int sbase = c16 * 16;
    int l15 = lane & 15, lg = lane >> 4;

    const unsigned short* kp = kb + ((long)b * T_ + sbase + l15) * H_;
    short8 bk0 = *(const short8*)(kp + lg * 8);
    short8 bk1 = *(const short8*)(kp + 32 + lg * 8);

    float M = -__builtin_inff(), d = 0.f;
    const unsigned short* qbase = qb + (long)b * T_ * H_;

    for (int t0 = sbase; t0 < T_; t0 += 16) {
        const unsigned short* qp = qbase + (long)(t0 + l15) * H_;
        short8 a0 = *(const short8*)(qp + lg * 8);
        short8 a1 = *(const short8*)(qp + 32 + lg * 8);
        f32x4 acc = (f32x4){0.f, 0.f, 0.f, 0.f};
        acc = __builtin_amdgcn_mfma_f32_16x16x32_bf16(a0, bk0, acc, 0, 0, 0);
        acc = __builtin_amdgcn_mfma_f32_16x16x32_bf16(a1, bk1, acc, 0, 0, 0);

        float sc[4];
        #pragma unroll
        for (int r = 0; r < 4; ++r) {
            sc[r] = acc[r] * SCALE;
            if (t0 == sbase && (lg * 4 + r) < l15) sc[r] = -__builtin_inff();
        }
        float mt = fmaxf(fmaxf(sc[0], sc[1]), fmaxf(sc[2], sc[3]));
        mt = fmaxf(mt, __shfl_xor(mt, 16, 64));
        mt = fmaxf(mt, __shfl_xor(mt, 32, 64));
        float newM = fmaxf(M, mt);
        float alpha = __expf(M - newM);     // first tile: exp(-inf)=0
        float s4 = __expf(sc[0] - newM) + __expf(sc[1] - newM) +
                   __expf(sc[2] - newM) + __expf(sc[3] - newM);
        d = d * alpha + s4;
        M = newM;
    }
    d += __shfl_xor(d, 16, 64);
    d += __shfl_xor(d, 32, 64);
    if (lane < 16) {
        colM[b * T_ + sbase + lane] = M;
        colR[b * T_ + sbase + lane] = 1.0f / d;
    }
}

// ---------------- kernel 3: out[t,h] = sum_{s<=t} exp(score-M[s])*R[s] * v[s,h] -----
// wave owns 16 q-rows x 64 h; no barriers (per-wave P LDS); balanced pairing
__global__ __launch_bounds__(256) void attn_out(const unsigned short* __restrict__ qb,
                                                const unsigned short* __restrict__ kb,
                                                const unsigned short* __restrict__ vt,
                                                const float* __restrict__ colM,
                                                const float* __restrict__ colR,
                                                float* __restrict__ out) {
    __shared__ unsigned short pl[4][16 * 72];   // per-wave P tile [16 t][64 s], pad 8
    int tid = threadIdx.x, lane = tid & 63, w = tid >> 6;
    int b = blockIdx.x >> 5, j = blockIdx.x & 31;
    int t16 = (w == 0) ? 2 * j : (w == 1) ? 127 - 2 * j : (w == 2) ? 2 * j + 1 : 126 - 2 * j;
    int t0 = t16 * 16;
    int l15 = lane & 15, lg = lane >> 4;

    const unsigned short* qp = qb + ((long)b * T_ + t0 + l15) * H_;
    short8 qa0 = *(const short8*)(qp + lg * 8);
    short8 qa1 = *(const short8*)(qp + 32 + lg * 8);

    f32x4 o[4];
    for (int i = 0; i < 4; ++i) o[i] = (f32x4){0.f, 0.f, 0.f, 0.f};
    unsigned short* myp = pl[w];

    const unsigned short* kbase = kb + (long)b * T_ * H_;
    const unsigned short* vbase = vt + (long)b * H_ * T_;
    const float* cM = colM + b * T_;
    const float* cR = colR + b * T_;

    int nst = (t0 + 15) / 64 + 1;
    for (int si = 0; si < nst; ++si) {
        int s0 = si * 64;
        // QK^T -> P (bf16 in per-wave LDS)
        #pragma unroll
        for (int st = 0; st < 4; ++st) {
            int sb = s0 + st * 16;
            const unsigned short* kp = kbase + (long)(sb + l15) * H_;
            short8 b0 = *(const short8*)(kp + lg * 8);
            short8 b1 = *(const short8*)(kp + 32 + lg * 8);
            f32x4 acc = (f32x4){0.f, 0.f, 0.f, 0.f};
            acc = __builtin_amdgcn_mfma_f32_16x16x32_bf16(qa0, b0, acc, 0, 0, 0);
            acc = __builtin_amdgcn_mfma_f32_16x16x32_bf16(qa1, b1, acc, 0, 0, 0);
            int s = sb + l15;
            float m = cM[s], rr = cR[s];
            #pragma unroll
            for (int r = 0; r < 4; ++r) {
                int t = t0 + lg * 4 + r;
                float p = __expf(acc[r] * SCALE - m) * rr;   // score recompute bit-identical -> p<=R
                if (s > t) p = 0.f;
                myp[(lg * 4 + r) * 72 + st * 16 + l15] = f2bf(p);
            }
        }
        // P @ V   (A = P[t][s], B = vt[h][s] i.e. V[s][h])
        short8 pa0 = *(const short8*)&myp[l15 * 72 + lg * 8];
        short8 pa1 = *(const short8*)&myp[l15 * 72 + 32 + lg * 8];
        #pragma unroll
        for (int ht = 0; ht < 4; ++ht) {
            const unsigned short* vp = vbase + (long)(ht * 16 + l15) * T_ + s0 + lg * 8;
            short8 v0 = *(const short8*)(vp);
            short8 v1 = *(const short8*)(vp + 32);
            o[ht] = __builtin_amdgcn_mfma_f32_16x16x32_bf16(pa0, v0, o[ht], 0, 0, 0);
            o[ht] = __builtin_amdgcn_mfma_f32_16x16x32_bf16(pa1, v1, o[ht], 0, 0, 0);
        }
    }

    float* ob = out + ((long)b * T_ + t0) * H_;
    #pragma unroll
    for (int ht = 0; ht < 4; ++ht)
        #pragma unroll
        for (int r = 0; r < 4; ++r)
            ob[(long)(lg * 4 + r) * H_ + ht * 16 + l15] = o[ht][r];
}

extern "C" void kernel_launch(void* const* d_in, const int* in_sizes, int n_in,
                              void* d_out, int out_size, void* d_ws, size_t ws_size,
                              hipStream_t stream) {
    const float* x  = (const float*)d_in[0];
    const float* Wk = (const float*)d_in[1];
    const float* Wq = (const float*)d_in[2];
    const float* Wv = (const float*)d_in[3];
    float* out = (float*)d_out;

    char* ws = (char*)d_ws;
    unsigned short* Wt = (unsigned short*)ws;                                  // 393216 B
    unsigned short* qb = (unsigned short*)(ws + 393216);                       // 2 MB
    unsigned short* kb = (unsigned short*)(ws + 393216 + 2097152);             // 2 MB
    unsigned short* vt = (unsigned short*)(ws + 393216 + 2 * 2097152);         // 2 MB
    float* colM = (float*)(ws + 393216 + 3 * 2097152);                         // 64 KB
    float* colR = colM + B_ * T_;                                              // 64 KB

    prep_w  <<<192, 256, 0, stream>>>(Wq, Wk, Wv, Wt);
    qkv_gemm<<<512, 256, 0, stream>>>(x, Wt, qb, kb, vt);
    col_stats<<<256, 256, 0, stream>>>(qb, kb, colM, colR);
    attn_out<<<256, 256, 0, stream>>>(qb, kb, vt, colM, colR, out);
}

// Round 2
// 155.018 us; speedup vs baseline: 1.1272x; 1.1272x over previous
//
#include <hip/hip_runtime.h>
#include <hip/hip_bf16.h>

typedef __attribute__((ext_vector_type(8))) short short8;   // bf16x8 MFMA frag
typedef __attribute__((ext_vector_type(4))) float f32x4;    // fp32x4 acc

#define B_  8
#define T_  2048
#define E_  1024
#define H_  64
#define SCALE 0.03125f   // 1024^-0.5
#define NINF (-__builtin_inff())

__device__ inline unsigned short f2bf(float f) {
    unsigned int u = __builtin_bit_cast(unsigned int, f);
    unsigned int r = (u + 0x7FFFu + ((u >> 16) & 1u)) >> 16;   // RNE
    return (unsigned short)r;
}
__device__ inline unsigned int packbf(float lo, float hi) {
    return (unsigned int)f2bf(lo) | ((unsigned int)f2bf(hi) << 16);
}
// online-softmax merge, safe for (-inf,0) empty partials
__device__ inline void mergeMD(float& M, float& d, float Mo, float dn) {
    float nM = fmaxf(M, Mo);
    if (nM > -1e37f) {
        d = d * __expf(M - nM) + dn * __expf(Mo - nM);
        M = nM;
    }
}

// ---------------- kernel 0: W fp32 [1024][64] -> Wt bf16 [192][1024] (transposed) ----
// Wt rows 0-63 = Wq cols, 64-127 = Wk, 128-191 = Wv.  Coalesced read via LDS tile.
__global__ __launch_bounds__(256) void prep_w(const float* __restrict__ Wq,
                                              const float* __restrict__ Wk,
                                              const float* __restrict__ Wv,
                                              unsigned short* __restrict__ Wt) {
    __shared__ float ls[64][65];
    int tid = threadIdx.x;
    int wsel = blockIdx.x >> 4, kt = blockIdx.x & 15;
    const float* W = (wsel == 0) ? Wq : (wsel == 1) ? Wk : Wv;
    int kr = tid >> 2, c4 = (tid & 3) * 16;
    const float* src = W + (long)(kt * 64 + kr) * H_ + c4;
    #pragma unroll
    for (int i = 0; i < 4; ++i) {
        float4 v = *(const float4*)(src + 4 * i);
        ls[kr][c4 + 4 * i + 0] = v.x; ls[kr][c4 + 4 * i + 1] = v.y;
        ls[kr][c4 + 4 * i + 2] = v.z; ls[kr][c4 + 4 * i + 3] = v.w;
    }
    __syncthreads();
    int c = tid >> 2, kk = (tid & 3) * 16;
    unsigned short* dst = Wt + (long)(wsel * 64 + c) * E_ + kt * 64 + kk;
    uint4 o1, o2;
    o1.x = packbf(ls[kk + 0][c], ls[kk + 1][c]);  o1.y = packbf(ls[kk + 2][c], ls[kk + 3][c]);
    o1.z = packbf(ls[kk + 4][c], ls[kk + 5][c]);  o1.w = packbf(ls[kk + 6][c], ls[kk + 7][c]);
    o2.x = packbf(ls[kk + 8][c], ls[kk + 9][c]);  o2.y = packbf(ls[kk + 10][c], ls[kk + 11][c]);
    o2.z = packbf(ls[kk + 12][c], ls[kk + 13][c]);o2.w = packbf(ls[kk + 14][c], ls[kk + 15][c]);
    *(uint4*)dst = o1;
    *(uint4*)(dst + 8) = o2;
}

// ---------------- kernel 1: QKV GEMM  [16384,1024] @ [1024,192] --------------------
// Block = 16 rows, 4 waves each own a K-quarter (256). No barriers in main loop:
// x -> registers (pack bf16), W B-frags straight from global (L2-hot).
// LDS reduction across the 4 K-partials at the end.
__global__ __launch_bounds__(256, 3) void qkv_gemm(const float* __restrict__ x,
                                                   const unsigned short* __restrict__ Wt,
                                                   unsigned short* __restrict__ qb,
                                                   unsigned short* __restrict__ kb,
                                                   unsigned short* __restrict__ vt) {
    __shared__ float red[2][16][196];   // 25088 B
    int tid = threadIdx.x, lane = tid & 63, w = tid >> 6;
    int l15 = lane & 15, lg = lane >> 4;
    int r0 = blockIdx.x * 16;
    int b = r0 >> 11, tb = r0 & 2047;

    const float*          xp = x  + (long)(r0 + l15) * E_ + w * 256 + lg * 8;
    const unsigned short* wp = Wt + (long)l15 * E_ + w * 256 + lg * 8;

    f32x4 acc[12];
    #pragma unroll
    for (int i = 0; i < 12; ++i) acc[i] = (f32x4){0.f, 0.f, 0.f, 0.f};

    #pragma unroll
    for (int kk = 0; kk < 8; ++kk) {
        float4 xa0 = *(const float4*)(xp + kk * 32);
        float4 xa1 = *(const float4*)(xp + kk * 32 + 4);
        uint4 ua;
        ua.x = packbf(xa0.x, xa0.y); ua.y = packbf(xa0.z, xa0.w);
        ua.z = packbf(xa1.x, xa1.y); ua.w = packbf(xa1.z, xa1.w);
        short8 a = __builtin_bit_cast(short8, ua);
        #pragma unroll
        for (int ct = 0; ct < 12; ++ct) {
            short8 bf = *(const short8*)(wp + (long)ct * 16 * E_ + kk * 32);
            acc[ct] = __builtin_amdgcn_mfma_f32_16x16x32_bf16(a, bf, acc[ct], 0, 0, 0);
        }
    }

    // reduce 4 K-partials: waves 2,3 write; waves 0,1 add; then combine buf0+buf1
    if (w >= 2) {
        #pragma unroll
        for (int ct = 0; ct < 12; ++ct)
            #pragma unroll
            for (int r = 0; r < 4; ++r)
                red[w - 2][lg * 4 + r][ct * 16 + l15] = acc[ct][r];
    }
    __syncthreads();
    if (w < 2) {
        #pragma unroll
        for (int ct = 0; ct < 12; ++ct)
            #pragma unroll
            for (int r = 0; r < 4; ++r)
                red[w][lg * 4 + r][ct * 16 + l15] += acc[ct][r];
    }
    __syncthreads();

    // output: 16 rows x 24 groups-of-8-cols = 384 units
    for (int u = tid; u < 384; u += 256) {
        int row = u / 24, g = u - row * 24;
        int c0 = g * 8;
        float4 s0 = *(const float4*)&red[0][row][c0];
        float4 s1 = *(const float4*)&red[0][row][c0 + 4];
        float4 t0 = *(const float4*)&red[1][row][c0];
        float4 t1 = *(const float4*)&red[1][row][c0 + 4];
        float v0 = s0.x + t0.x, v1 = s0.y + t0.y, v2 = s0.z + t0.z, v3 = s0.w + t0.w;
        float v4 = s1.x + t1.x, v5 = s1.y + t1.y, v6 = s1.z + t1.z, v7 = s1.w + t1.w;
        if (g < 16) {
            unsigned short* dst = ((g < 8) ? qb : kb) + ((long)b * T_ + tb + row) * H_ + (g & 7) * 8;
            uint4 o;
            o.x = packbf(v0, v1); o.y = packbf(v2, v3);
            o.z = packbf(v4, v5); o.w = packbf(v6, v7);
            *(uint4*)dst = o;
        } else {
            int h0 = (g - 16) * 8;
            unsigned short* dst = vt + ((long)b * H_ + h0) * T_ + tb + row;
            dst[0 * T_] = f2bf(v0); dst[1 * T_] = f2bf(v1);
            dst[2 * T_] = f2bf(v2); dst[3 * T_] = f2bf(v3);
            dst[4 * T_] = f2bf(v4); dst[5 * T_] = f2bf(v5);
            dst[6 * T_] = f2bf(v6); dst[7 * T_] = f2bf(v7);
        }
    }
}

// ---------------- kernel 2: per-key-column max & sum over queries t>=s --------------
// Block = one 16-column group; 4 waves split the t-range (stride 64).
// Per-lane deferred (M,d): no cross-lane ops in the loop.
__global__ __launch_bounds__(256) void col_stats(const unsigned short* __restrict__ qb,
                                                 const unsigned short* __restrict__ kb,
                                                 float* __restrict__ colM,
                                                 float* __restrict__ colR) {
    __shared__ float lM[4][16], lD[4][16];
    int tid = threadIdx.x, lane = tid & 63, w = tid >> 6;
    int b = blockIdx.x >> 7, c16 = blockIdx.x & 127;
    int sbase = c16 * 16;
    int l15 = lane & 15, lg = lane >> 4;

    const unsigned short* kp = kb + ((long)b * T_ + sbase + l15) * H_;
    short8 bk0 = *(const short8*)(kp + lg * 8);
    short8 bk1 = *(const short8*)(kp + 32 + lg * 8);

    float M = NINF, d = 0.f;
    const unsigned short* qbase = qb + (long)b * T_ * H_;

    for (int t0 = sbase + 16 * w; t0 < T_; t0 += 64) {
        const unsigned short* qp = qbase + (long)(t0 + l15) * H_;
        short8 a0 = *(const short8*)(qp + lg * 8);
        short8 a1 = *(const short8*)(qp + 32 + lg * 8);
        f32x4 acc = (f32x4){0.f, 0.f, 0.f, 0.f};
        acc = __builtin_amdgcn_mfma_f32_16x16x32_bf16(a0, bk0, acc, 0, 0, 0);
        acc = __builtin_amdgcn_mfma_f32_16x16x32_bf16(a1, bk1, acc, 0, 0, 0);

        float sc[4];
        #pragma unroll
        for (int r = 0; r < 4; ++r) {
            sc[r] = acc[r] * SCALE;
            if (t0 == sbase && (lg * 4 + r) < l15) sc[r] = NINF;
        }
        float m4 = fmaxf(fmaxf(sc[0], sc[1]), fmaxf(sc[2], sc[3]));
        float nM = fmaxf(M, m4);
        if (nM > -1e37f) {
            float s4 = __expf(sc[0] - nM) + __expf(sc[1] - nM) +
                       __expf(sc[2] - nM) + __expf(sc[3] - nM);
            d = d * __expf(M - nM) + s4;
            M = nM;
        }
    }
    // intra-wave reduce across the 4 lg row-groups
    float Mo = __shfl_xor(M, 16, 64), dn = __shfl_xor(d, 16, 64);
    mergeMD(M, d, Mo, dn);
    Mo = __shfl_xor(M, 32, 64); dn = __shfl_xor(d, 32, 64);
    mergeMD(M, d, Mo, dn);
    if (lane < 16) { lM[w][lane] = M; lD[w][lane] = d; }
    __syncthreads();
    if (tid < 16) {
        float Mf = NINF, df = 0.f;
        #pragma unroll
        for (int i = 0; i < 4; ++i) mergeMD(Mf, df, lM[i][tid], lD[i][tid]);
        colM[b * T_ + sbase + tid] = Mf;
        colR[b * T_ + sbase + tid] = 1.0f / df;
    }
}

// ---------------- kernel 3: out[t,h] = sum_{s<=t} exp(score-M[s])*R[s] * v[s,h] -----
// Block = one 16-query-row group; 4 waves split the 64-wide s-tiles (stride 4).
// Per-wave P LDS, LDS output reduction at the end.
__global__ __launch_bounds__(256) void attn_out(const unsigned short* __restrict__ qb,
                                                const unsigned short* __restrict__ kb,
                                                const unsigned short* __restrict__ vt,
                                                const float* __restrict__ colM,
                                                const float* __restrict__ colR,
                                                float* __restrict__ out) {
    __shared__ unsigned short pl[4][16 * 72];   // per-wave P tile [16 t][64 s]
    __shared__ float osum[3][16][68];           // cross-wave output partials
    int tid = threadIdx.x, lane = tid & 63, w = tid >> 6;
    int b = blockIdx.x >> 7, t16 = blockIdx.x & 127;
    int t0 = t16 * 16;
    int l15 = lane & 15, lg = lane >> 4;

    const unsigned short* qp = qb + ((long)b * T_ + t0 + l15) * H_;
    short8 qa0 = *(const short8*)(qp + lg * 8);
    short8 qa1 = *(const short8*)(qp + 32 + lg * 8);

    f32x4 o[4];
    #pragma unroll
    for (int i = 0; i < 4; ++i) o[i] = (f32x4){0.f, 0.f, 0.f, 0.f};
    unsigned short* myp = pl[w];

    const unsigned short* kbase = kb + (long)b * T_ * H_;
    const unsigned short* vbase = vt + (long)b * H_ * T_;
    const float* cM = colM + b * T_;
    const float* cR = colR + b * T_;

    int nst = t16 / 4 + 1;   // number of 64-wide s-tiles touching s <= t0+15
    for (int si = w; si < nst; si += 4) {
        int s0 = si * 64;
        #pragma unroll
        for (int st = 0; st < 4; ++st) {
            int sb = s0 + st * 16;
            const unsigned short* kp = kbase + (long)(sb + l15) * H_;
            short8 b0 = *(const short8*)(kp + lg * 8);
            short8 b1 = *(const short8*)(kp + 32 + lg * 8);
            f32x4 acc = (f32x4){0.f, 0.f, 0.f, 0.f};
            acc = __builtin_amdgcn_mfma_f32_16x16x32_bf16(qa0, b0, acc, 0, 0, 0);
            acc = __builtin_amdgcn_mfma_f32_16x16x32_bf16(qa1, b1, acc, 0, 0, 0);
            int s = sb + l15;
            float m = cM[s], rr = cR[s];
            #pragma unroll
            for (int r = 0; r < 4; ++r) {
                int t = t0 + lg * 4 + r;
                float p = __expf(acc[r] * SCALE - m) * rr;   // bit-identical score -> p bounded
                if (s > t) p = 0.f;
                myp[(lg * 4 + r) * 72 + st * 16 + l15] = f2bf(p);
            }
        }
        short8 pa0 = *(const short8*)&myp[l15 * 72 + lg * 8];
        short8 pa1 = *(const short8*)&myp[l15 * 72 + 32 + lg * 8];
        #pragma unroll
        for (int ht = 0; ht < 4; ++ht) {
            const unsigned short* vp = vbase + (long)(ht * 16 + l15) * T_ + s0 + lg * 8;
            short8 v0 = *(const short8*)(vp);
            short8 v1 = *(const short8*)(vp + 32);
            o[ht] = __builtin_amdgcn_mfma_f32_16x16x32_bf16(pa0, v0, o[ht], 0, 0, 0);
            o[ht] = __builtin_amdgcn_mfma_f32_16x16x32_bf16(pa1, v1, o[ht], 0, 0, 0);
        }
    }

    if (w > 0) {
        #pragma unroll
        for (int ht = 0; ht < 4; ++ht)
            #pragma unroll
            for (int r = 0; r < 4; ++r)
                osum[w - 1][lg * 4 + r][ht * 16 + l15] = o[ht][r];
    }
    __syncthreads();
    if (w == 0) {
        float* ob = out + ((long)b * T_ + t0) * H_;
        #pragma unroll
        for (int ht = 0; ht < 4; ++ht)
            #pragma unroll
            for (int r = 0; r < 4; ++r) {
                int rr_ = lg * 4 + r, cc = ht * 16 + l15;
                float v = o[ht][r] + osum[0][rr_][cc] + osum[1][rr_][cc] + osum[2][rr_][cc];
                ob[(long)rr_ * H_ + cc] = v;
            }
    }
}

extern "C" void kernel_launch(void* const* d_in, const int* in_sizes, int n_in,
                              void* d_out, int out_size, void* d_ws, size_t ws_size,
                              hipStream_t stream) {
    const float* x  = (const float*)d_in[0];
    const float* Wk = (const float*)d_in[1];
    const float* Wq = (const float*)d_in[2];
    const float* Wv = (const float*)d_in[3];
    float* out = (float*)d_out;

    char* ws = (char*)d_ws;
    unsigned short* Wt = (unsigned short*)ws;                                  // 393216 B
    unsigned short* qb = (unsigned short*)(ws + 393216);                       // 2 MB
    unsigned short* kb = (unsigned short*)(ws + 393216 + 2097152);             // 2 MB
    unsigned short* vt = (unsigned short*)(ws + 393216 + 2 * 2097152);         // 2 MB
    float* colM = (float*)(ws + 393216 + 3 * 2097152);                         // 64 KB
    float* colR = colM + B_ * T_;                                              // 64 KB

    prep_w   <<<48,   256, 0, stream>>>(Wq, Wk, Wv, Wt);
    qkv_gemm <<<1024, 256, 0, stream>>>(x, Wt, qb, kb, vt);
    col_stats<<<1024, 256, 0, stream>>>(qb, kb, colM, colR);
    attn_out <<<1024, 256, 0, stream>>>(qb, kb, vt, colM, colR, out);
}

// Round 3
// 121.247 us; speedup vs baseline: 1.4412x; 1.2785x over previous
//
#include <hip/hip_runtime.h>
#include <hip/hip_bf16.h>

typedef __attribute__((ext_vector_type(8))) short short8;   // bf16x8 MFMA frag
typedef __attribute__((ext_vector_type(4))) float f32x4;    // fp32x4 acc

#define B_  8
#define T_  2048
#define E_  1024
#define H_  64
#define SCALE 0.03125f   // 1024^-0.5
#define NINF (-__builtin_inff())

__device__ inline unsigned short f2bf(float f) {
    unsigned int u = __builtin_bit_cast(unsigned int, f);
    unsigned int r = (u + 0x7FFFu + ((u >> 16) & 1u)) >> 16;   // RNE
    return (unsigned short)r;
}
__device__ inline unsigned int packbf(float lo, float hi) {
    return (unsigned int)f2bf(lo) | ((unsigned int)f2bf(hi) << 16);
}
__device__ inline void mergeMD(float& M, float& d, float Mo, float dn) {
    float nM = fmaxf(M, Mo);
    if (nM > -1e37f) {
        d = d * __expf(M - nM) + dn * __expf(Mo - nM);
        M = nM;
    }
}
__device__ inline void glds16(const void* g, void* l) {
    __builtin_amdgcn_global_load_lds((const __attribute__((address_space(1))) void*)g,
                                     (__attribute__((address_space(3))) void*)l, 16, 0, 0);
}

// ---------------- kernel 0: W fp32 [1024][64] -> Wt bf16 [192][1024] (transposed) ----
__global__ __launch_bounds__(256) void prep_w(const float* __restrict__ Wq,
                                              const float* __restrict__ Wk,
                                              const float* __restrict__ Wv,
                                              unsigned short* __restrict__ Wt) {
    __shared__ float ls[64][65];
    int tid = threadIdx.x;
    int wsel = blockIdx.x >> 4, kt = blockIdx.x & 15;
    const float* W = (wsel == 0) ? Wq : (wsel == 1) ? Wk : Wv;
    int kr = tid >> 2, c4 = (tid & 3) * 16;
    const float* src = W + (long)(kt * 64 + kr) * H_ + c4;
    #pragma unroll
    for (int i = 0; i < 4; ++i) {
        float4 v = *(const float4*)(src + 4 * i);
        ls[kr][c4 + 4 * i + 0] = v.x; ls[kr][c4 + 4 * i + 1] = v.y;
        ls[kr][c4 + 4 * i + 2] = v.z; ls[kr][c4 + 4 * i + 3] = v.w;
    }
    __syncthreads();
    int c = tid >> 2, kk = (tid & 3) * 16;
    unsigned short* dst = Wt + (long)(wsel * 64 + c) * E_ + kt * 64 + kk;
    uint4 o1, o2;
    o1.x = packbf(ls[kk + 0][c], ls[kk + 1][c]);  o1.y = packbf(ls[kk + 2][c], ls[kk + 3][c]);
    o1.z = packbf(ls[kk + 4][c], ls[kk + 5][c]);  o1.w = packbf(ls[kk + 6][c], ls[kk + 7][c]);
    o2.x = packbf(ls[kk + 8][c], ls[kk + 9][c]);  o2.y = packbf(ls[kk + 10][c], ls[kk + 11][c]);
    o2.z = packbf(ls[kk + 12][c], ls[kk + 13][c]);o2.w = packbf(ls[kk + 14][c], ls[kk + 15][c]);
    *(uint4*)dst = o1;
    *(uint4*)(dst + 8) = o2;
}

// ---------------- kernel 1: QKV GEMM  [16384,1024] @ [1024,192] --------------------
// Block = 32 rows x 192 cols, full K. 4 waves = 2 row-groups x 2 col-halves.
// W: global_load_lds (dbuf, XOR-swizzled k-chunks). x: reg-stage -> bf16 -> padded LDS.
// One barrier per k-step (BK=64).
__global__ __launch_bounds__(256) void qkv_gemm(const float* __restrict__ x,
                                                const unsigned short* __restrict__ Wt,
                                                unsigned short* __restrict__ qb,
                                                unsigned short* __restrict__ kb,
                                                unsigned short* __restrict__ vt) {
    __shared__ unsigned short wlds[2][192 * 64];   // 49152 B, linear (glds dest)
    __shared__ unsigned short xlds[2][32 * 72];    // 9216 B, padded stride 144B

    int tid = threadIdx.x, lane = tid & 63, w = tid >> 6;
    int l15 = lane & 15, lg = lane >> 4;
    int wr = w & 1, wc = w >> 1;
    int r0 = blockIdx.x * 32;
    int b = r0 >> 11, tb = r0 & 2047;

    // W staging: wave w stages rows 48w..48w+47 in 6 glds calls (8 rows/call).
    // LDS linear slot s holds global k-chunk (s ^ (row&7))  [bank swizzle]
    int l8 = lane >> 3, s8 = lane & 7;
    int swz = s8 ^ l8;                      // row&7 == lane>>3 (call base row % 8 == 0)
    const unsigned short* wg = Wt + (long)(48 * w + l8) * E_ + swz * 8;
    unsigned short* wl0 = &wlds[0][(48 * w) * 64];
    unsigned short* wl1 = &wlds[1][(48 * w) * 64];

    // x staging: thread -> row xr, chunk xc (8 fp32 -> 8 bf16)
    int xr = tid >> 3, xc = tid & 7;
    const float* xg = x + (long)(r0 + xr) * E_ + xc * 8;

    f32x4 acc[6];
    #pragma unroll
    for (int i = 0; i < 6; ++i) acc[i] = (f32x4){0.f, 0.f, 0.f, 0.f};

    // prologue: stage k-step 0
    #pragma unroll
    for (int j = 0; j < 6; ++j)
        glds16(wg + (long)(8 * j) * E_, wl0 + (8 * j) * 64);
    {
        float4 xa = *(const float4*)xg;
        float4 xb = *(const float4*)(xg + 4);
        uint4 ua;
        ua.x = packbf(xa.x, xa.y); ua.y = packbf(xa.z, xa.w);
        ua.z = packbf(xb.x, xb.y); ua.w = packbf(xb.z, xb.w);
        *(uint4*)((char*)&xlds[0][0] + xr * 144 + xc * 16) = ua;
    }

    float4 xa, xb;
    for (int ks = 0; ks < 16; ++ks) {
        int cur = ks & 1;
        __syncthreads();                       // buf `cur` ready (vm+lgkm drained)
        if (ks < 15) {
            int kp = (ks + 1) * 64;
            unsigned short* wldst = cur ? wl0 : wl1;
            #pragma unroll
            for (int j = 0; j < 6; ++j)
                glds16(wg + (long)(8 * j) * E_ + kp, wldst + (8 * j) * 64);
            xa = *(const float4*)(xg + kp);
            xb = *(const float4*)(xg + kp + 4);
        }
        // compute from buf `cur`
        const char* wb = (const char*)&wlds[cur][0];
        const char* xsb = (const char*)&xlds[cur][0];
        #pragma unroll
        for (int kk2 = 0; kk2 < 2; ++kk2) {
            short8 a = *(const short8*)(xsb + (16 * wr + l15) * 144 + kk2 * 64 + lg * 16);
            #pragma unroll
            for (int ct = 0; ct < 6; ++ct) {
                int c = 96 * wc + 16 * ct + l15;
                int sp = (kk2 * 4 + lg) ^ (c & 7);
                short8 bf = *(const short8*)(wb + c * 128 + sp * 16);
                acc[ct] = __builtin_amdgcn_mfma_f32_16x16x32_bf16(a, bf, acc[ct], 0, 0, 0);
            }
        }
        if (ks < 15) {
            uint4 ua;
            ua.x = packbf(xa.x, xa.y); ua.y = packbf(xa.z, xa.w);
            ua.z = packbf(xb.x, xb.y); ua.w = packbf(xb.z, xb.w);
            *(uint4*)((char*)&xlds[cur ^ 1][0] + xr * 144 + xc * 16) = ua;
        }
    }

    // q/k epilogue: direct stores (cols 0..127)
    #pragma unroll
    for (int ct = 0; ct < 6; ++ct) {
        int col = 96 * wc + 16 * ct + l15;
        if (col < 128) {
            unsigned short* dst = (col < 64) ? qb : kb;
            int n = col & 63;
            #pragma unroll
            for (int r = 0; r < 4; ++r) {
                int t = tb + 16 * wr + lg * 4 + r;
                dst[((long)b * T_ + t) * H_ + n] = f2bf(acc[ct][r]);
            }
        }
    }
    // v epilogue: transpose via LDS (alias wlds[0]; last compute read wlds[1])
    float* vbuf = (float*)&wlds[0][0];        // [32][68] fp32
    if (wc == 1) {
        #pragma unroll
        for (int ct = 2; ct < 6; ++ct) {
            int h = 16 * (ct - 2) + l15;
            #pragma unroll
            for (int r = 0; r < 4; ++r)
                vbuf[(16 * wr + lg * 4 + r) * 68 + h] = acc[ct][r];
        }
    }
    __syncthreads();
    {
        int h = tid >> 2, tc = (tid & 3) * 8;
        uint4 o;
        o.x = packbf(vbuf[(tc + 0) * 68 + h], vbuf[(tc + 1) * 68 + h]);
        o.y = packbf(vbuf[(tc + 2) * 68 + h], vbuf[(tc + 3) * 68 + h]);
        o.z = packbf(vbuf[(tc + 4) * 68 + h], vbuf[(tc + 5) * 68 + h]);
        o.w = packbf(vbuf[(tc + 6) * 68 + h], vbuf[(tc + 7) * 68 + h]);
        *(uint4*)&vt[((long)b * H_ + h) * T_ + tb + tc] = o;
    }
}

// ---------------- kernel 2: per-key-column max & sum over queries t>=s --------------
// Block = one 16-column group; 4 waves split t (stride 64); next-tile reg prefetch.
__global__ __launch_bounds__(256) void col_stats(const unsigned short* __restrict__ qb,
                                                 const unsigned short* __restrict__ kb,
                                                 float* __restrict__ colM,
                                                 float* __restrict__ colR) {
    __shared__ float lM[4][16], lD[4][16];
    int tid = threadIdx.x, lane = tid & 63, w = tid >> 6;
    int b = blockIdx.x >> 7, c16 = blockIdx.x & 127;
    int sbase = c16 * 16;
    int l15 = lane & 15, lg = lane >> 4;

    const unsigned short* kp = kb + ((long)b * T_ + sbase + l15) * H_;
    short8 bk0 = *(const short8*)(kp + lg * 8);
    short8 bk1 = *(const short8*)(kp + 32 + lg * 8);

    float M = NINF, d = 0.f;
    const unsigned short* qbase = qb + (long)b * T_ * H_;

    int t0 = sbase + 16 * w;
    int tc0 = (t0 < T_) ? t0 : 0;
    const unsigned short* qp = qbase + (long)(tc0 + l15) * H_ + lg * 8;
    short8 a0 = *(const short8*)qp;
    short8 a1 = *(const short8*)(qp + 32);

    for (; t0 < T_; t0 += 64) {
        int tn = (t0 + 64 < T_) ? t0 + 64 : t0;            // clamped prefetch addr
        const unsigned short* qn = qbase + (long)(tn + l15) * H_ + lg * 8;
        short8 n0 = *(const short8*)qn;
        short8 n1 = *(const short8*)(qn + 32);

        f32x4 acc = (f32x4){0.f, 0.f, 0.f, 0.f};
        acc = __builtin_amdgcn_mfma_f32_16x16x32_bf16(a0, bk0, acc, 0, 0, 0);
        acc = __builtin_amdgcn_mfma_f32_16x16x32_bf16(a1, bk1, acc, 0, 0, 0);

        float sc[4];
        #pragma unroll
        for (int r = 0; r < 4; ++r) {
            sc[r] = acc[r] * SCALE;
            if (t0 == sbase && (lg * 4 + r) < l15) sc[r] = NINF;
        }
        float m4 = fmaxf(fmaxf(sc[0], sc[1]), fmaxf(sc[2], sc[3]));
        float nM = fmaxf(M, m4);
        if (nM > -1e37f) {
            float s4 = __expf(sc[0] - nM) + __expf(sc[1] - nM) +
                       __expf(sc[2] - nM) + __expf(sc[3] - nM);
            d = d * __expf(M - nM) + s4;
            M = nM;
        }
        a0 = n0; a1 = n1;
    }
    float Mo = __shfl_xor(M, 16, 64), dn = __shfl_xor(d, 16, 64);
    mergeMD(M, d, Mo, dn);
    Mo = __shfl_xor(M, 32, 64); dn = __shfl_xor(d, 32, 64);
    mergeMD(M, d, Mo, dn);
    if (lane < 16) { lM[w][lane] = M; lD[w][lane] = d; }
    __syncthreads();
    if (tid < 16) {
        float Mf = NINF, df = 0.f;
        #pragma unroll
        for (int i = 0; i < 4; ++i) mergeMD(Mf, df, lM[i][tid], lD[i][tid]);
        colM[b * T_ + sbase + tid] = Mf;
        colR[b * T_ + sbase + tid] = 1.0f / df;
    }
}

// ---------------- kernel 3: out[t,h] = sum_{s<=t} exp(score-M[s])*R[s] * v[s,h] -----
// Block = one 16-row q-group (t16 reversed: big blocks first); 4 waves split s-tiles.
// All 16 K/V loads of an s-tile issued upfront (batched latency).
__global__ __launch_bounds__(256, 4) void attn_out(const unsigned short* __restrict__ qb,
                                                   const unsigned short* __restrict__ kb,
                                                   const unsigned short* __restrict__ vt,
                                                   const float* __restrict__ colM,
                                                   const float* __restrict__ colR,
                                                   float* __restrict__ out) {
    __shared__ unsigned short pl[4][16 * 72];
    __shared__ float osum[3][16][68];
    int tid = threadIdx.x, lane = tid & 63, w = tid >> 6;
    int b = blockIdx.x >> 7;
    int t16 = 127 - (blockIdx.x & 127);     // reversed: most-work blocks dispatch first
    int t0 = t16 * 16;
    int l15 = lane & 15, lg = lane >> 4;

    const unsigned short* qp = qb + ((long)b * T_ + t0 + l15) * H_;
    short8 qa0 = *(const short8*)(qp + lg * 8);
    short8 qa1 = *(const short8*)(qp + 32 + lg * 8);

    f32x4 o[4];
    #pragma unroll
    for (int i = 0; i < 4; ++i) o[i] = (f32x4){0.f, 0.f, 0.f, 0.f};
    unsigned short* myp = pl[w];

    const unsigned short* kbase = kb + (long)b * T_ * H_;
    const unsigned short* vbase = vt + (long)b * H_ * T_;
    const float* cM = colM + b * T_;
    const float* cR = colR + b * T_;

    int nst = t16 / 4 + 1;
    for (int si = w; si < nst; si += 4) {
        int s0 = si * 64;
        // batch-issue all K loads (8) and V loads (8) for this s-tile
        const unsigned short* kp0 = kbase + (long)(s0 + l15) * H_ + lg * 8;
        short8 kf[8];
        #pragma unroll
        for (int st = 0; st < 4; ++st) {
            kf[2 * st]     = *(const short8*)(kp0 + (long)st * 16 * H_);
            kf[2 * st + 1] = *(const short8*)(kp0 + (long)st * 16 * H_ + 32);
        }
        const unsigned short* vp0 = vbase + (long)l15 * T_ + s0 + lg * 8;
        short8 vf[8];
        #pragma unroll
        for (int ht = 0; ht < 4; ++ht) {
            vf[2 * ht]     = *(const short8*)(vp0 + (long)ht * 16 * T_);
            vf[2 * ht + 1] = *(const short8*)(vp0 + (long)ht * 16 * T_ + 32);
        }
        float cMv[4], cRv[4];
        #pragma unroll
        for (int st = 0; st < 4; ++st) {
            int s = s0 + st * 16 + l15;
            cMv[st] = cM[s]; cRv[st] = cR[s];
        }
        // QK^T + normalize -> P (per-wave LDS)
        #pragma unroll
        for (int st = 0; st < 4; ++st) {
            f32x4 acc = (f32x4){0.f, 0.f, 0.f, 0.f};
            acc = __builtin_amdgcn_mfma_f32_16x16x32_bf16(qa0, kf[2 * st], acc, 0, 0, 0);
            acc = __builtin_amdgcn_mfma_f32_16x16x32_bf16(qa1, kf[2 * st + 1], acc, 0, 0, 0);
            int s = s0 + st * 16 + l15;
            #pragma unroll
            for (int r = 0; r < 4; ++r) {
                int t = t0 + lg * 4 + r;
                float p = __expf(acc[r] * SCALE - cMv[st]) * cRv[st];
                if (s > t) p = 0.f;
                myp[(lg * 4 + r) * 72 + st * 16 + l15] = f2bf(p);
            }
        }
        // P @ V
        short8 pa0 = *(const short8*)&myp[l15 * 72 + lg * 8];
        short8 pa1 = *(const short8*)&myp[l15 * 72 + 32 + lg * 8];
        #pragma unroll
        for (int ht = 0; ht < 4; ++ht) {
            o[ht] = __builtin_amdgcn_mfma_f32_16x16x32_bf16(pa0, vf[2 * ht], o[ht], 0, 0, 0);
            o[ht] = __builtin_amdgcn_mfma_f32_16x16x32_bf16(pa1, vf[2 * ht + 1], o[ht], 0, 0, 0);
        }
    }

    if (w > 0) {
        #pragma unroll
        for (int ht = 0; ht < 4; ++ht)
            #pragma unroll
            for (int r = 0; r < 4; ++r)
                osum[w - 1][lg * 4 + r][ht * 16 + l15] = o[ht][r];
    }
    __syncthreads();
    if (w == 0) {
        float* ob = out + ((long)b * T_ + t0) * H_;
        #pragma unroll
        for (int ht = 0; ht < 4; ++ht)
            #pragma unroll
            for (int r = 0; r < 4; ++r) {
                int rr_ = lg * 4 + r, cc = ht * 16 + l15;
                float v = o[ht][r] + osum[0][rr_][cc] + osum[1][rr_][cc] + osum[2][rr_][cc];
                ob[(long)rr_ * H_ + cc] = v;
            }
    }
}

extern "C" void kernel_launch(void* const* d_in, const int* in_sizes, int n_in,
                              void* d_out, int out_size, void* d_ws, size_t ws_size,
                              hipStream_t stream) {
    const float* x  = (const float*)d_in[0];
    const float* Wk = (const float*)d_in[1];
    const float* Wq = (const float*)d_in[2];
    const float* Wv = (const float*)d_in[3];
    float* out = (float*)d_out;

    char* ws = (char*)d_ws;
    unsigned short* Wt = (unsigned short*)ws;                                  // 393216 B
    unsigned short* qb = (unsigned short*)(ws + 393216);                       // 2 MB
    unsigned short* kb = (unsigned short*)(ws + 393216 + 2097152);             // 2 MB
    unsigned short* vt = (unsigned short*)(ws + 393216 + 2 * 2097152);         // 2 MB
    float* colM = (float*)(ws + 393216 + 3 * 2097152);                         // 64 KB
    float* colR = colM + B_ * T_;                                              // 64 KB

    prep_w   <<<48,   256, 0, stream>>>(Wq, Wk, Wv, Wt);
    qkv_gemm <<<512,  256, 0, stream>>>(x, Wt, qb, kb, vt);
    col_stats<<<1024, 256, 0, stream>>>(qb, kb, colM, colR);
    attn_out <<<1024, 256, 0, stream>>>(qb, kb, vt, colM, colR, out);
}

// Round 4
// 89.767 us; speedup vs baseline: 1.9466x; 1.3507x over previous
//
#include <hip/hip_runtime.h>
#include <hip/hip_bf16.h>

typedef __attribute__((ext_vector_type(8))) short short8;   // bf16x8 MFMA frag
typedef __attribute__((ext_vector_type(4))) float f32x4;    // fp32x4 acc

#define B_  8
#define T_  2048
#define E_  1024
#define H_  64
#define SCALE 0.03125f   // 1024^-0.5
#define NINF (-__builtin_inff())

__device__ inline unsigned short f2bf(float f) {
    unsigned int u = __builtin_bit_cast(unsigned int, f);
    unsigned int r = (u + 0x7FFFu + ((u >> 16) & 1u)) >> 16;   // RNE
    return (unsigned short)r;
}
__device__ inline unsigned int packbf(float lo, float hi) {
    return (unsigned int)f2bf(lo) | ((unsigned int)f2bf(hi) << 16);
}
__device__ inline void mergeMD(float& M, float& d, float Mo, float dn) {
    float nM = fmaxf(M, Mo);
    if (nM > -1e37f) {
        d = d * __expf(M - nM) + dn * __expf(Mo - nM);
        M = nM;
    }
}
__device__ inline void glds16(const void* g, void* l) {
    __builtin_amdgcn_global_load_lds((const __attribute__((address_space(1))) void*)g,
                                     (__attribute__((address_space(3))) void*)l, 16, 0, 0);
}

// ---------------- kernel 0: W fp32 [1024][64] -> Wt bf16 [192][1024] (transposed) ----
__global__ __launch_bounds__(256) void prep_w(const float* __restrict__ Wq,
                                              const float* __restrict__ Wk,
                                              const float* __restrict__ Wv,
                                              unsigned short* __restrict__ Wt) {
    __shared__ float ls[64][65];
    int tid = threadIdx.x;
    int wsel = blockIdx.x >> 4, kt = blockIdx.x & 15;
    const float* W = (wsel == 0) ? Wq : (wsel == 1) ? Wk : Wv;
    int kr = tid >> 2, c4 = (tid & 3) * 16;
    const float* src = W + (long)(kt * 64 + kr) * H_ + c4;
    #pragma unroll
    for (int i = 0; i < 4; ++i) {
        float4 v = *(const float4*)(src + 4 * i);
        ls[kr][c4 + 4 * i + 0] = v.x; ls[kr][c4 + 4 * i + 1] = v.y;
        ls[kr][c4 + 4 * i + 2] = v.z; ls[kr][c4 + 4 * i + 3] = v.w;
    }
    __syncthreads();
    int c = tid >> 2, kk = (tid & 3) * 16;
    unsigned short* dst = Wt + (long)(wsel * 64 + c) * E_ + kt * 64 + kk;
    uint4 o1, o2;
    o1.x = packbf(ls[kk + 0][c], ls[kk + 1][c]);  o1.y = packbf(ls[kk + 2][c], ls[kk + 3][c]);
    o1.z = packbf(ls[kk + 4][c], ls[kk + 5][c]);  o1.w = packbf(ls[kk + 6][c], ls[kk + 7][c]);
    o2.x = packbf(ls[kk + 8][c], ls[kk + 9][c]);  o2.y = packbf(ls[kk + 10][c], ls[kk + 11][c]);
    o2.z = packbf(ls[kk + 12][c], ls[kk + 13][c]);o2.w = packbf(ls[kk + 14][c], ls[kk + 15][c]);
    *(uint4*)dst = o1;
    *(uint4*)(dst + 8) = o2;
}

// ---------------- kernel 1: QKV GEMM  [16384,1024] @ [1024,192] --------------------
__global__ __launch_bounds__(256) void qkv_gemm(const float* __restrict__ x,
                                                const unsigned short* __restrict__ Wt,
                                                unsigned short* __restrict__ qb,
                                                unsigned short* __restrict__ kb,
                                                unsigned short* __restrict__ vt) {
    __shared__ unsigned short wlds[2][192 * 64];   // 49152 B, linear (glds dest)
    __shared__ unsigned short xlds[2][32 * 72];    // 9216 B, padded stride 144B

    int tid = threadIdx.x, lane = tid & 63, w = tid >> 6;
    int l15 = lane & 15, lg = lane >> 4;
    int wr = w & 1, wc = w >> 1;
    int r0 = blockIdx.x * 32;
    int b = r0 >> 11, tb = r0 & 2047;

    int l8 = lane >> 3, s8 = lane & 7;
    int swz = s8 ^ l8;
    const unsigned short* wg = Wt + (long)(48 * w + l8) * E_ + swz * 8;
    unsigned short* wl0 = &wlds[0][(48 * w) * 64];
    unsigned short* wl1 = &wlds[1][(48 * w) * 64];

    int xr = tid >> 3, xc = tid & 7;
    const float* xg = x + (long)(r0 + xr) * E_ + xc * 8;

    f32x4 acc[6];
    #pragma unroll
    for (int i = 0; i < 6; ++i) acc[i] = (f32x4){0.f, 0.f, 0.f, 0.f};

    #pragma unroll
    for (int j = 0; j < 6; ++j)
        glds16(wg + (long)(8 * j) * E_, wl0 + (8 * j) * 64);
    {
        float4 xa = *(const float4*)xg;
        float4 xb = *(const float4*)(xg + 4);
        uint4 ua;
        ua.x = packbf(xa.x, xa.y); ua.y = packbf(xa.z, xa.w);
        ua.z = packbf(xb.x, xb.y); ua.w = packbf(xb.z, xb.w);
        *(uint4*)((char*)&xlds[0][0] + xr * 144 + xc * 16) = ua;
    }

    float4 xa, xb;
    for (int ks = 0; ks < 16; ++ks) {
        int cur = ks & 1;
        __syncthreads();
        if (ks < 15) {
            int kp = (ks + 1) * 64;
            unsigned short* wldst = cur ? wl0 : wl1;
            #pragma unroll
            for (int j = 0; j < 6; ++j)
                glds16(wg + (long)(8 * j) * E_ + kp, wldst + (8 * j) * 64);
            xa = *(const float4*)(xg + kp);
            xb = *(const float4*)(xg + kp + 4);
        }
        const char* wb = (const char*)&wlds[cur][0];
        const char* xsb = (const char*)&xlds[cur][0];
        #pragma unroll
        for (int kk2 = 0; kk2 < 2; ++kk2) {
            short8 a = *(const short8*)(xsb + (16 * wr + l15) * 144 + kk2 * 64 + lg * 16);
            #pragma unroll
            for (int ct = 0; ct < 6; ++ct) {
                int c = 96 * wc + 16 * ct + l15;
                int sp = (kk2 * 4 + lg) ^ (c & 7);
                short8 bf = *(const short8*)(wb + c * 128 + sp * 16);
                acc[ct] = __builtin_amdgcn_mfma_f32_16x16x32_bf16(a, bf, acc[ct], 0, 0, 0);
            }
        }
        if (ks < 15) {
            uint4 ua;
            ua.x = packbf(xa.x, xa.y); ua.y = packbf(xa.z, xa.w);
            ua.z = packbf(xb.x, xb.y); ua.w = packbf(xb.z, xb.w);
            *(uint4*)((char*)&xlds[cur ^ 1][0] + xr * 144 + xc * 16) = ua;
        }
    }

    #pragma unroll
    for (int ct = 0; ct < 6; ++ct) {
        int col = 96 * wc + 16 * ct + l15;
        if (col < 128) {
            unsigned short* dst = (col < 64) ? qb : kb;
            int n = col & 63;
            #pragma unroll
            for (int r = 0; r < 4; ++r) {
                int t = tb + 16 * wr + lg * 4 + r;
                dst[((long)b * T_ + t) * H_ + n] = f2bf(acc[ct][r]);
            }
        }
    }
    float* vbuf = (float*)&wlds[0][0];
    if (wc == 1) {
        #pragma unroll
        for (int ct = 2; ct < 6; ++ct) {
            int h = 16 * (ct - 2) + l15;
            #pragma unroll
            for (int r = 0; r < 4; ++r)
                vbuf[(16 * wr + lg * 4 + r) * 68 + h] = acc[ct][r];
        }
    }
    __syncthreads();
    {
        int h = tid >> 2, tc = (tid & 3) * 8;
        uint4 o;
        o.x = packbf(vbuf[(tc + 0) * 68 + h], vbuf[(tc + 1) * 68 + h]);
        o.y = packbf(vbuf[(tc + 2) * 68 + h], vbuf[(tc + 3) * 68 + h]);
        o.z = packbf(vbuf[(tc + 4) * 68 + h], vbuf[(tc + 5) * 68 + h]);
        o.w = packbf(vbuf[(tc + 6) * 68 + h], vbuf[(tc + 7) * 68 + h]);
        *(uint4*)&vt[((long)b * H_ + h) * T_ + tb + tc] = o;
    }
}

// ---------------- kernel 2: per-key-column max & sum over queries t>=s --------------
__global__ __launch_bounds__(256) void col_stats(const unsigned short* __restrict__ qb,
                                                 const unsigned short* __restrict__ kb,
                                                 float* __restrict__ colM,
                                                 float* __restrict__ colR) {
    __shared__ float lM[4][16], lD[4][16];
    int tid = threadIdx.x, lane = tid & 63, w = tid >> 6;
    int b = blockIdx.x >> 7, c16 = blockIdx.x & 127;
    int sbase = c16 * 16;
    int l15 = lane & 15, lg = lane >> 4;

    const unsigned short* kp = kb + ((long)b * T_ + sbase + l15) * H_;
    short8 bk0 = *(const short8*)(kp + lg * 8);
    short8 bk1 = *(const short8*)(kp + 32 + lg * 8);

    float M = NINF, d = 0.f;
    const unsigned short* qbase = qb + (long)b * T_ * H_;

    int t0 = sbase + 16 * w;
    int tc0 = (t0 < T_) ? t0 : 0;
    const unsigned short* qp = qbase + (long)(tc0 + l15) * H_ + lg * 8;
    short8 a0 = *(const short8*)qp;
    short8 a1 = *(const short8*)(qp + 32);

    for (; t0 < T_; t0 += 64) {
        int tn = (t0 + 64 < T_) ? t0 + 64 : t0;
        const unsigned short* qn = qbase + (long)(tn + l15) * H_ + lg * 8;
        short8 n0 = *(const short8*)qn;
        short8 n1 = *(const short8*)(qn + 32);

        f32x4 acc = (f32x4){0.f, 0.f, 0.f, 0.f};
        acc = __builtin_amdgcn_mfma_f32_16x16x32_bf16(a0, bk0, acc, 0, 0, 0);
        acc = __builtin_amdgcn_mfma_f32_16x16x32_bf16(a1, bk1, acc, 0, 0, 0);

        float sc[4];
        #pragma unroll
        for (int r = 0; r < 4; ++r) {
            sc[r] = acc[r] * SCALE;
            if (t0 == sbase && (lg * 4 + r) < l15) sc[r] = NINF;
        }
        float m4 = fmaxf(fmaxf(sc[0], sc[1]), fmaxf(sc[2], sc[3]));
        float nM = fmaxf(M, m4);
        if (nM > -1e37f) {
            float s4 = __expf(sc[0] - nM) + __expf(sc[1] - nM) +
                       __expf(sc[2] - nM) + __expf(sc[3] - nM);
            d = d * __expf(M - nM) + s4;
            M = nM;
        }
        a0 = n0; a1 = n1;
    }
    float Mo = __shfl_xor(M, 16, 64), dn = __shfl_xor(d, 16, 64);
    mergeMD(M, d, Mo, dn);
    Mo = __shfl_xor(M, 32, 64); dn = __shfl_xor(d, 32, 64);
    mergeMD(M, d, Mo, dn);
    if (lane < 16) { lM[w][lane] = M; lD[w][lane] = d; }
    __syncthreads();
    if (tid < 16) {
        float Mf = NINF, df = 0.f;
        #pragma unroll
        for (int i = 0; i < 4; ++i) mergeMD(Mf, df, lM[i][tid], lD[i][tid]);
        colM[b * T_ + sbase + tid] = Mf;
        colR[b * T_ + sbase + tid] = 1.0f / df;
    }
}

// ---------------- kernel 3: out[t,h] = sum_{s<=t} exp(score-M[s])*R[s] * v[s,h] -----
// Block = (b, 32 q-rows). 4 waves = (qw = w&1: 16 q-rows, sw = w>>1: 32-wide s-half).
// K/V 64-tile shared in LDS, double-buffered global_load_lds (XOR-swizzled source).
// One barrier per s-tile; per-wave P LDS; sw-pair output reduction at end.
__global__ __launch_bounds__(256) void attn_out(const unsigned short* __restrict__ qb,
                                                const unsigned short* __restrict__ kb,
                                                const unsigned short* __restrict__ vt,
                                                const float* __restrict__ colM,
                                                const float* __restrict__ colR,
                                                float* __restrict__ out) {
    __shared__ unsigned short kv[2][8192];        // [buf][ K 64x64 | V 64x64 ]  32 KB
    __shared__ unsigned short pbuf[4][16 * 40];   // per-wave P [16 q][32 s] pad -> 5 KB

    int tid = threadIdx.x, lane = tid & 63, w = tid >> 6;
    int qw = w & 1, sw = w >> 1;
    int l15 = lane & 15, lg = lane >> 4;
    int b = blockIdx.x & 7;
    int j = 63 - (blockIdx.x >> 3);               // big q-tiles dispatch first
    int t0 = j * 32;

    const unsigned short* kbase = kb + (long)b * T_ * H_;
    const unsigned short* vbase = vt + (long)b * H_ * T_;
    const float* cM = colM + b * T_;
    const float* cR = colR + b * T_;

    // q fragments (16 rows of this wave's q-group)
    const unsigned short* qp = qb + ((long)b * T_ + t0 + qw * 16 + l15) * H_ + lg * 8;
    short8 qa0 = *(const short8*)qp;
    short8 qa1 = *(const short8*)(qp + 32);

    // staging addresses: wave w stages K rows w*16..+15 and V rows w*16..+15 (2 glds each)
    int l8 = lane >> 3, s8 = lane & 7;
    int swz8 = (s8 ^ l8) * 8;
    const unsigned short* kg = kbase + (long)(w * 16 + l8) * H_ + swz8;   // + (s0)*H_
    const unsigned short* vg = vbase + (long)(w * 16 + l8) * T_ + swz8;   // + s0
    unsigned short* kd0 = &kv[0][w * 16 * 64];
    unsigned short* vd0 = &kv[0][4096 + w * 16 * 64];
    unsigned short* kd1 = &kv[1][w * 16 * 64];
    unsigned short* vd1 = &kv[1][4096 + w * 16 * 64];

    f32x4 o[4];
    #pragma unroll
    for (int i = 0; i < 4; ++i) o[i] = (f32x4){0.f, 0.f, 0.f, 0.f};
    unsigned short* myp = pbuf[w];

    int nst = j / 2 + 1;

    // prologue: stage tile 0 into buf 0
    glds16(kg, kd0);  glds16(kg + 8 * H_, kd0 + 8 * 64);
    glds16(vg, vd0);  glds16(vg + 8 * T_, vd0 + 8 * 64);

    for (int si = 0; si < nst; ++si) {
        int cur = si & 1;
        __syncthreads();                           // buf cur ready (vm drained)
        if (si + 1 < nst) {
            int sn = (si + 1) * 64;
            unsigned short* kd = cur ? kd0 : kd1;
            unsigned short* vd = cur ? vd0 : vd1;
            glds16(kg + (long)sn * H_, kd);
            glds16(kg + (long)sn * H_ + 8 * H_, kd + 8 * 64);
            glds16(vg + sn, vd);
            glds16(vg + sn + 8 * T_, vd + 8 * 64);
        }
        int s0 = si * 64;
        const unsigned short* kt = &kv[cur][0];
        const unsigned short* vtl = &kv[cur][4096];

        // QK^T for this wave's 16 q x 32 s -> P
        #pragma unroll
        for (int ct = 0; ct < 2; ++ct) {
            int row = sw * 32 + ct * 16 + l15;
            short8 k0 = *(const short8*)&kt[row * 64 + ((0 + lg) ^ (row & 7)) * 8];
            short8 k1 = *(const short8*)&kt[row * 64 + ((4 + lg) ^ (row & 7)) * 8];
            f32x4 acc = (f32x4){0.f, 0.f, 0.f, 0.f};
            acc = __builtin_amdgcn_mfma_f32_16x16x32_bf16(qa0, k0, acc, 0, 0, 0);
            acc = __builtin_amdgcn_mfma_f32_16x16x32_bf16(qa1, k1, acc, 0, 0, 0);
            int s = s0 + row;
            float m = cM[s], rr = cR[s];
            #pragma unroll
            for (int r = 0; r < 4; ++r) {
                int t = t0 + qw * 16 + lg * 4 + r;
                float p = __expf(acc[r] * SCALE - m) * rr;
                if (s > t) p = 0.f;
                myp[(lg * 4 + r) * 40 + ct * 16 + l15] = f2bf(p);
            }
        }
        // P @ V (k = this wave's 32 s)
        short8 pa = *(const short8*)&myp[l15 * 40 + lg * 8];
        #pragma unroll
        for (int ht = 0; ht < 4; ++ht) {
            int vrow = ht * 16 + l15;
            short8 vf = *(const short8*)&vtl[vrow * 64 + ((sw * 4 + lg) ^ (vrow & 7)) * 8];
            o[ht] = __builtin_amdgcn_mfma_f32_16x16x32_bf16(pa, vf, o[ht], 0, 0, 0);
        }
    }

    // reduce the two s-halves; write output
    __syncthreads();
    float* rbuf = (float*)&kv[0][0];               // [32 q][68] f32 = 8.7 KB
    if (sw == 1) {
        #pragma unroll
        for (int ht = 0; ht < 4; ++ht)
            #pragma unroll
            for (int r = 0; r < 4; ++r)
                rbuf[(qw * 16 + lg * 4 + r) * 68 + ht * 16 + l15] = o[ht][r];
    }
    __syncthreads();
    if (sw == 0) {
        float* ob = out + ((long)b * T_ + t0 + qw * 16) * H_;
        #pragma unroll
        for (int ht = 0; ht < 4; ++ht)
            #pragma unroll
            for (int r = 0; r < 4; ++r) {
                int rr_ = lg * 4 + r, cc = ht * 16 + l15;
                ob[(long)rr_ * H_ + cc] = o[ht][r] + rbuf[(qw * 16 + rr_) * 68 + cc];
            }
    }
}

extern "C" void kernel_launch(void* const* d_in, const int* in_sizes, int n_in,
                              void* d_out, int out_size, void* d_ws, size_t ws_size,
                              hipStream_t stream) {
    const float* x  = (const float*)d_in[0];
    const float* Wk = (const float*)d_in[1];
    const float* Wq = (const float*)d_in[2];
    const float* Wv = (const float*)d_in[3];
    float* out = (float*)d_out;

    char* ws = (char*)d_ws;
    unsigned short* Wt = (unsigned short*)ws;                                  // 393216 B
    unsigned short* qb = (unsigned short*)(ws + 393216);                       // 2 MB
    unsigned short* kb = (unsigned short*)(ws + 393216 + 2097152);             // 2 MB
    unsigned short* vt = (unsigned short*)(ws + 393216 + 2 * 2097152);         // 2 MB
    float* colM = (float*)(ws + 393216 + 3 * 2097152);                         // 64 KB
    float* colR = colM + B_ * T_;                                              // 64 KB

    prep_w   <<<48,   256, 0, stream>>>(Wq, Wk, Wv, Wt);
    qkv_gemm <<<512,  256, 0, stream>>>(x, Wt, qb, kb, vt);
    col_stats<<<1024, 256, 0, stream>>>(qb, kb, colM, colR);
    attn_out <<<512,  256, 0, stream>>>(qb, kb, vt, colM, colR, out);
}

// Round 5
// 79.194 us; speedup vs baseline: 2.2064x; 1.1335x over previous
//
#include <hip/hip_runtime.h>
#include <hip/hip_bf16.h>

typedef __attribute__((ext_vector_type(8))) short short8;   // bf16x8 MFMA frag
typedef __attribute__((ext_vector_type(4))) float f32x4;    // fp32x4 acc

#define B_  8
#define T_  2048
#define E_  1024
#define H_  64
#define SCALE 0.03125f   // 1024^-0.5
#define NINF (-__builtin_inff())

__device__ inline unsigned short f2bf(float f) {
    unsigned int u = __builtin_bit_cast(unsigned int, f);
    unsigned int r = (u + 0x7FFFu + ((u >> 16) & 1u)) >> 16;   // RNE
    return (unsigned short)r;
}
__device__ inline unsigned int packbf(float lo, float hi) {
    return (unsigned int)f2bf(lo) | ((unsigned int)f2bf(hi) << 16);
}
__device__ inline void mergeMD(float& M, float& d, float Mo, float dn) {
    float nM = fmaxf(M, Mo);
    if (nM > -1e37f) {
        d = d * __expf(M - nM) + dn * __expf(Mo - nM);
        M = nM;
    }
}
__device__ inline void glds16(const void* g, void* l) {
    __builtin_amdgcn_global_load_lds((const __attribute__((address_space(1))) void*)g,
                                     (__attribute__((address_space(3))) void*)l, 16, 0, 0);
}

// ---------------- kernel 0: W fp32 [1024][64] -> Wt bf16 [192][1024] (transposed) ----
__global__ __launch_bounds__(256) void prep_w(const float* __restrict__ Wq,
                                              const float* __restrict__ Wk,
                                              const float* __restrict__ Wv,
                                              unsigned short* __restrict__ Wt) {
    __shared__ float ls[64][65];
    int tid = threadIdx.x;
    int wsel = blockIdx.x >> 4, kt = blockIdx.x & 15;
    const float* W = (wsel == 0) ? Wq : (wsel == 1) ? Wk : Wv;
    int kr = tid >> 2, c4 = (tid & 3) * 16;
    const float* src = W + (long)(kt * 64 + kr) * H_ + c4;
    #pragma unroll
    for (int i = 0; i < 4; ++i) {
        float4 v = *(const float4*)(src + 4 * i);
        ls[kr][c4 + 4 * i + 0] = v.x; ls[kr][c4 + 4 * i + 1] = v.y;
        ls[kr][c4 + 4 * i + 2] = v.z; ls[kr][c4 + 4 * i + 3] = v.w;
    }
    __syncthreads();
    int c = tid >> 2, kk = (tid & 3) * 16;
    unsigned short* dst = Wt + (long)(wsel * 64 + c) * E_ + kt * 64 + kk;
    uint4 o1, o2;
    o1.x = packbf(ls[kk + 0][c], ls[kk + 1][c]);  o1.y = packbf(ls[kk + 2][c], ls[kk + 3][c]);
    o1.z = packbf(ls[kk + 4][c], ls[kk + 5][c]);  o1.w = packbf(ls[kk + 6][c], ls[kk + 7][c]);
    o2.x = packbf(ls[kk + 8][c], ls[kk + 9][c]);  o2.y = packbf(ls[kk + 10][c], ls[kk + 11][c]);
    o2.z = packbf(ls[kk + 12][c], ls[kk + 13][c]);o2.w = packbf(ls[kk + 14][c], ls[kk + 15][c]);
    *(uint4*)dst = o1;
    *(uint4*)(dst + 8) = o2;
}

// ---------------- kernel 1: QKV GEMM  [16384,1024] @ [1024,192] --------------------
__global__ __launch_bounds__(256) void qkv_gemm(const float* __restrict__ x,
                                                const unsigned short* __restrict__ Wt,
                                                unsigned short* __restrict__ qb,
                                                unsigned short* __restrict__ kb,
                                                unsigned short* __restrict__ vt) {
    __shared__ unsigned short wlds[2][192 * 64];   // 49152 B, linear (glds dest)
    __shared__ unsigned short xlds[2][32 * 72];    // 9216 B, padded stride 144B

    int tid = threadIdx.x, lane = tid & 63, w = tid >> 6;
    int l15 = lane & 15, lg = lane >> 4;
    int wr = w & 1, wc = w >> 1;
    int r0 = blockIdx.x * 32;
    int b = r0 >> 11, tb = r0 & 2047;

    int l8 = lane >> 3, s8 = lane & 7;
    int swz = s8 ^ l8;
    const unsigned short* wg = Wt + (long)(48 * w + l8) * E_ + swz * 8;
    unsigned short* wl0 = &wlds[0][(48 * w) * 64];
    unsigned short* wl1 = &wlds[1][(48 * w) * 64];

    int xr = tid >> 3, xc = tid & 7;
    const float* xg = x + (long)(r0 + xr) * E_ + xc * 8;

    f32x4 acc[6];
    #pragma unroll
    for (int i = 0; i < 6; ++i) acc[i] = (f32x4){0.f, 0.f, 0.f, 0.f};

    #pragma unroll
    for (int j = 0; j < 6; ++j)
        glds16(wg + (long)(8 * j) * E_, wl0 + (8 * j) * 64);
    {
        float4 xa = *(const float4*)xg;
        float4 xb = *(const float4*)(xg + 4);
        uint4 ua;
        ua.x = packbf(xa.x, xa.y); ua.y = packbf(xa.z, xa.w);
        ua.z = packbf(xb.x, xb.y); ua.w = packbf(xb.z, xb.w);
        *(uint4*)((char*)&xlds[0][0] + xr * 144 + xc * 16) = ua;
    }

    float4 xa, xb;
    for (int ks = 0; ks < 16; ++ks) {
        int cur = ks & 1;
        __syncthreads();
        if (ks < 15) {
            int kp = (ks + 1) * 64;
            unsigned short* wldst = cur ? wl0 : wl1;
            #pragma unroll
            for (int j = 0; j < 6; ++j)
                glds16(wg + (long)(8 * j) * E_ + kp, wldst + (8 * j) * 64);
            xa = *(const float4*)(xg + kp);
            xb = *(const float4*)(xg + kp + 4);
        }
        const char* wb = (const char*)&wlds[cur][0];
        const char* xsb = (const char*)&xlds[cur][0];
        #pragma unroll
        for (int kk2 = 0; kk2 < 2; ++kk2) {
            short8 a = *(const short8*)(xsb + (16 * wr + l15) * 144 + kk2 * 64 + lg * 16);
            #pragma unroll
            for (int ct = 0; ct < 6; ++ct) {
                int c = 96 * wc + 16 * ct + l15;
                int sp = (kk2 * 4 + lg) ^ (c & 7);
                short8 bf = *(const short8*)(wb + c * 128 + sp * 16);
                acc[ct] = __builtin_amdgcn_mfma_f32_16x16x32_bf16(a, bf, acc[ct], 0, 0, 0);
            }
        }
        if (ks < 15) {
            uint4 ua;
            ua.x = packbf(xa.x, xa.y); ua.y = packbf(xa.z, xa.w);
            ua.z = packbf(xb.x, xb.y); ua.w = packbf(xb.z, xb.w);
            *(uint4*)((char*)&xlds[cur ^ 1][0] + xr * 144 + xc * 16) = ua;
        }
    }

    #pragma unroll
    for (int ct = 0; ct < 6; ++ct) {
        int col = 96 * wc + 16 * ct + l15;
        if (col < 128) {
            unsigned short* dst = (col < 64) ? qb : kb;
            int n = col & 63;
            #pragma unroll
            for (int r = 0; r < 4; ++r) {
                int t = tb + 16 * wr + lg * 4 + r;
                dst[((long)b * T_ + t) * H_ + n] = f2bf(acc[ct][r]);
            }
        }
    }
    float* vbuf = (float*)&wlds[0][0];
    if (wc == 1) {
        #pragma unroll
        for (int ct = 2; ct < 6; ++ct) {
            int h = 16 * (ct - 2) + l15;
            #pragma unroll
            for (int r = 0; r < 4; ++r)
                vbuf[(16 * wr + lg * 4 + r) * 68 + h] = acc[ct][r];
        }
    }
    __syncthreads();
    {
        int h = tid >> 2, tc = (tid & 3) * 8;
        uint4 o;
        o.x = packbf(vbuf[(tc + 0) * 68 + h], vbuf[(tc + 1) * 68 + h]);
        o.y = packbf(vbuf[(tc + 2) * 68 + h], vbuf[(tc + 3) * 68 + h]);
        o.z = packbf(vbuf[(tc + 4) * 68 + h], vbuf[(tc + 5) * 68 + h]);
        o.w = packbf(vbuf[(tc + 6) * 68 + h], vbuf[(tc + 7) * 68 + h]);
        *(uint4*)&vt[((long)b * H_ + h) * T_ + tb + tc] = o;
    }
}

// ---------------- kernel 2: per-key-column max & sum over queries t>=s --------------
// Block = one 16-column group; 4 waves split t (stride 128, TWO independent chains).
__global__ __launch_bounds__(256) void col_stats(const unsigned short* __restrict__ qb,
                                                 const unsigned short* __restrict__ kb,
                                                 float* __restrict__ colM,
                                                 float* __restrict__ colR) {
    __shared__ float lM[4][16], lD[4][16];
    int tid = threadIdx.x, lane = tid & 63, w = tid >> 6;
    int b = blockIdx.x >> 7, c16 = blockIdx.x & 127;
    int sbase = c16 * 16;
    int l15 = lane & 15, lg = lane >> 4;

    const unsigned short* kp = kb + ((long)b * T_ + sbase + l15) * H_;
    short8 bk0 = *(const short8*)(kp + lg * 8);
    short8 bk1 = *(const short8*)(kp + 32 + lg * 8);

    float M1 = NINF, d1 = 0.f, M2 = NINF, d2 = 0.f;
    const unsigned short* qbase = qb + (long)b * T_ * H_;

    for (int t0 = sbase + 16 * w; t0 < T_; t0 += 128) {
        int t0b = t0 + 64;
        bool has2 = (t0b < T_);
        int t0c = has2 ? t0b : t0;
        const unsigned short* qp1 = qbase + (long)(t0 + l15) * H_ + lg * 8;
        const unsigned short* qp2 = qbase + (long)(t0c + l15) * H_ + lg * 8;
        short8 a0 = *(const short8*)qp1;
        short8 a1 = *(const short8*)(qp1 + 32);
        short8 c0 = *(const short8*)qp2;
        short8 c1 = *(const short8*)(qp2 + 32);

        f32x4 acc1 = (f32x4){0.f, 0.f, 0.f, 0.f};
        acc1 = __builtin_amdgcn_mfma_f32_16x16x32_bf16(a0, bk0, acc1, 0, 0, 0);
        acc1 = __builtin_amdgcn_mfma_f32_16x16x32_bf16(a1, bk1, acc1, 0, 0, 0);
        f32x4 acc2 = (f32x4){0.f, 0.f, 0.f, 0.f};
        acc2 = __builtin_amdgcn_mfma_f32_16x16x32_bf16(c0, bk0, acc2, 0, 0, 0);
        acc2 = __builtin_amdgcn_mfma_f32_16x16x32_bf16(c1, bk1, acc2, 0, 0, 0);

        float sc[4];
        #pragma unroll
        for (int r = 0; r < 4; ++r) {
            sc[r] = acc1[r] * SCALE;
            if (t0 == sbase && (lg * 4 + r) < l15) sc[r] = NINF;
        }
        float m4 = fmaxf(fmaxf(sc[0], sc[1]), fmaxf(sc[2], sc[3]));
        float nM = fmaxf(M1, m4);
        if (nM > -1e37f) {
            float s4 = __expf(sc[0] - nM) + __expf(sc[1] - nM) +
                       __expf(sc[2] - nM) + __expf(sc[3] - nM);
            d1 = d1 * __expf(M1 - nM) + s4;
            M1 = nM;
        }
        if (has2) {
            float tc[4];
            #pragma unroll
            for (int r = 0; r < 4; ++r) tc[r] = acc2[r] * SCALE;
            float m4b = fmaxf(fmaxf(tc[0], tc[1]), fmaxf(tc[2], tc[3]));
            float nM2 = fmaxf(M2, m4b);
            float s4b = __expf(tc[0] - nM2) + __expf(tc[1] - nM2) +
                        __expf(tc[2] - nM2) + __expf(tc[3] - nM2);
            d2 = d2 * __expf(M2 - nM2) + s4b;
            M2 = nM2;
        }
    }
    mergeMD(M1, d1, M2, d2);
    float Mo = __shfl_xor(M1, 16, 64), dn = __shfl_xor(d1, 16, 64);
    mergeMD(M1, d1, Mo, dn);
    Mo = __shfl_xor(M1, 32, 64); dn = __shfl_xor(d1, 32, 64);
    mergeMD(M1, d1, Mo, dn);
    if (lane < 16) { lM[w][lane] = M1; lD[w][lane] = d1; }
    __syncthreads();
    if (tid < 16) {
        float Mf = NINF, df = 0.f;
        #pragma unroll
        for (int i = 0; i < 4; ++i) mergeMD(Mf, df, lM[i][tid], lD[i][tid]);
        colM[b * T_ + sbase + tid] = Mf;
        colR[b * T_ + sbase + tid] = 1.0f / df;
    }
}

// ---------------- kernel 3: out[t,h] = sum_{s<=t} exp(score-M[s])*R[s] * v[s,h] -----
// Block = (p, b, 32 q-rows): the (b,j) pair splits s-tiles by parity p (balanced).
// 4 waves = (qw: 16 q-rows, sw: 32-wide s-half). K/V 64-tile dbuf via glds.
// Output: fp32 atomic add onto zeroed d_out (2 commutative adders -> deterministic).
__global__ __launch_bounds__(256, 4) void attn_out(const unsigned short* __restrict__ qb,
                                                   const unsigned short* __restrict__ kb,
                                                   const unsigned short* __restrict__ vt,
                                                   const float* __restrict__ colM,
                                                   const float* __restrict__ colR,
                                                   float* __restrict__ out) {
    __shared__ unsigned short kv[2][8192];        // [buf][ K 64x64 | V 64x64 ]  32 KB
    __shared__ unsigned short pbuf[4][16 * 40];   // per-wave P [16 q][32 s]      5 KB

    int tid = threadIdx.x, lane = tid & 63, w = tid >> 6;
    int qw = w & 1, sw = w >> 1;
    int l15 = lane & 15, lg = lane >> 4;
    int idx = blockIdx.x;
    int p = idx & 1;
    int b = (idx >> 1) & 7;
    int j = 63 - (idx >> 4);                      // big q-tiles dispatch first
    int t0 = j * 32;

    const unsigned short* kbase = kb + (long)b * T_ * H_;
    const unsigned short* vbase = vt + (long)b * H_ * T_;
    const float* cM = colM + b * T_;
    const float* cR = colR + b * T_;

    const unsigned short* qp = qb + ((long)b * T_ + t0 + qw * 16 + l15) * H_ + lg * 8;
    short8 qa0 = *(const short8*)qp;
    short8 qa1 = *(const short8*)(qp + 32);

    int l8 = lane >> 3, s8 = lane & 7;
    int swz8 = (s8 ^ l8) * 8;
    const unsigned short* kg = kbase + (long)(w * 16 + l8) * H_ + swz8;
    const unsigned short* vg = vbase + (long)(w * 16 + l8) * T_ + swz8;
    unsigned short* kd0 = &kv[0][w * 16 * 64];
    unsigned short* vd0 = &kv[0][4096 + w * 16 * 64];
    unsigned short* kd1 = &kv[1][w * 16 * 64];
    unsigned short* vd1 = &kv[1][4096 + w * 16 * 64];

    f32x4 o[4];
    #pragma unroll
    for (int i = 0; i < 4; ++i) o[i] = (f32x4){0.f, 0.f, 0.f, 0.f};
    unsigned short* myp = pbuf[w];

    int nstt = j / 2 + 1;

    if (p < nstt) {   // prologue: stage tile p into buf 0
        int s0 = p * 64;
        glds16(kg + (long)s0 * H_, kd0);  glds16(kg + (long)s0 * H_ + 8 * H_, kd0 + 8 * 64);
        glds16(vg + s0, vd0);             glds16(vg + s0 + 8 * T_, vd0 + 8 * 64);
    }

    int cnt = 0;
    for (int si = p; si < nstt; si += 2, ++cnt) {
        int cur = cnt & 1;
        __syncthreads();                           // buf cur ready (vm drained)
        if (si + 2 < nstt) {
            int sn = (si + 2) * 64;
            unsigned short* kd = cur ? kd0 : kd1;
            unsigned short* vd = cur ? vd0 : vd1;
            glds16(kg + (long)sn * H_, kd);
            glds16(kg + (long)sn * H_ + 8 * H_, kd + 8 * 64);
            glds16(vg + sn, vd);
            glds16(vg + sn + 8 * T_, vd + 8 * 64);
        }
        int s0 = si * 64;
        const unsigned short* kt = &kv[cur][0];
        const unsigned short* vtl = &kv[cur][4096];

        #pragma unroll
        for (int ct = 0; ct < 2; ++ct) {
            int row = sw * 32 + ct * 16 + l15;
            short8 k0 = *(const short8*)&kt[row * 64 + ((0 + lg) ^ (row & 7)) * 8];
            short8 k1 = *(const short8*)&kt[row * 64 + ((4 + lg) ^ (row & 7)) * 8];
            f32x4 acc = (f32x4){0.f, 0.f, 0.f, 0.f};
            acc = __builtin_amdgcn_mfma_f32_16x16x32_bf16(qa0, k0, acc, 0, 0, 0);
            acc = __builtin_amdgcn_mfma_f32_16x16x32_bf16(qa1, k1, acc, 0, 0, 0);
            int s = s0 + row;
            float m = cM[s], rr = cR[s];
            #pragma unroll
            for (int r = 0; r < 4; ++r) {
                int t = t0 + qw * 16 + lg * 4 + r;
                float pv = __expf(acc[r] * SCALE - m) * rr;
                if (s > t) pv = 0.f;
                myp[(lg * 4 + r) * 40 + ct * 16 + l15] = f2bf(pv);
            }
        }
        short8 pa = *(const short8*)&myp[l15 * 40 + lg * 8];
        #pragma unroll
        for (int ht = 0; ht < 4; ++ht) {
            int vrow = ht * 16 + l15;
            short8 vf = *(const short8*)&vtl[vrow * 64 + ((sw * 4 + lg) ^ (vrow & 7)) * 8];
            o[ht] = __builtin_amdgcn_mfma_f32_16x16x32_bf16(pa, vf, o[ht], 0, 0, 0);
        }
    }

    // reduce the two s-halves; atomic-add output
    __syncthreads();
    float* rbuf = (float*)&kv[0][0];               // [32 q][68] f32
    if (sw == 1) {
        #pragma unroll
        for (int ht = 0; ht < 4; ++ht)
            #pragma unroll
            for (int r = 0; r < 4; ++r)
                rbuf[(qw * 16 + lg * 4 + r) * 68 + ht * 16 + l15] = o[ht][r];
    }
    __syncthreads();
    if (sw == 0) {
        float* ob = out + ((long)b * T_ + t0 + qw * 16) * H_;
        #pragma unroll
        for (int ht = 0; ht < 4; ++ht)
            #pragma unroll
            for (int r = 0; r < 4; ++r) {
                int rr_ = lg * 4 + r, cc = ht * 16 + l15;
                unsafeAtomicAdd(&ob[(long)rr_ * H_ + cc],
                                o[ht][r] + rbuf[(qw * 16 + rr_) * 68 + cc]);
            }
    }
}

extern "C" void kernel_launch(void* const* d_in, const int* in_sizes, int n_in,
                              void* d_out, int out_size, void* d_ws, size_t ws_size,
                              hipStream_t stream) {
    const float* x  = (const float*)d_in[0];
    const float* Wk = (const float*)d_in[1];
    const float* Wq = (const float*)d_in[2];
    const float* Wv = (const float*)d_in[3];
    float* out = (float*)d_out;

    char* ws = (char*)d_ws;
    unsigned short* Wt = (unsigned short*)ws;                                  // 393216 B
    unsigned short* qb = (unsigned short*)(ws + 393216);                       // 2 MB
    unsigned short* kb = (unsigned short*)(ws + 393216 + 2097152);             // 2 MB
    unsigned short* vt = (unsigned short*)(ws + 393216 + 2 * 2097152);         // 2 MB
    float* colM = (float*)(ws + 393216 + 3 * 2097152);                         // 64 KB
    float* colR = colM + B_ * T_;                                              // 64 KB

    hipMemsetAsync(out, 0, (size_t)out_size * sizeof(float), stream);
    prep_w   <<<48,   256, 0, stream>>>(Wq, Wk, Wv, Wt);
    qkv_gemm <<<512,  256, 0, stream>>>(x, Wt, qb, kb, vt);
    col_stats<<<1024, 256, 0, stream>>>(qb, kb, colM, colR);
    attn_out <<<1024, 256, 0, stream>>>(qb, kb, vt, colM, colR, out);
}